// Round 13
// baseline (380.234 us; speedup 1.0000x reference)
//
#include <hip/hip_runtime.h>
#include <hip/hip_bf16.h>
#include <stdint.h>

// GraphConv x2 — round 13: r10 base (ILP-8 gather, best=363us) + two fusions:
//   (a) fill ∥ gemm1: one heterogeneous launch (fill is memory-stall, gemm1 is
//       VALU-bound; disjoint outputs) — hides gemm1 inside fill.
//   (b) gemm2 fused into gather1 epilogue (correctness proven r8), now with
//       ILP-8 gather + 1 row/wave full grid (r8's slowness was ILP-4 + stride-6).
//   Pipeline: hist,scan1-3 -> [fill ∥ gemm1] -> gather1_fused -> gather2
// N=100000, E=1600000, D=64

#define D 64
#define SCAN_CHUNK 1024

typedef unsigned int   u32;
typedef unsigned short u16;

__device__ __forceinline__ float bf2f(u16 v) {
    return __uint_as_float(((u32)v) << 16);
}
__device__ __forceinline__ u16 f2bf(float f) {
    u32 u = __float_as_uint(f);
    u32 r = (u + 0x7fffu + ((u >> 16) & 1u)) >> 16;   // round-to-nearest-even
    return (u16)r;
}

// ---------------- CSR build (proven) ----------------
__global__ __launch_bounds__(256) void hist_kernel(
    const int* __restrict__ ei, int* __restrict__ deg, int E_)
{
    int e = blockIdx.x * 256 + threadIdx.x;
    if (e >= E_) return;
    atomicAdd(&deg[ei[E_ + e]], 1);
}

__global__ __launch_bounds__(256) void scan1_kernel(
    const int* __restrict__ deg, int* __restrict__ loc, int* __restrict__ partial, int n)
{
    __shared__ int wsum[4];
    int t = threadIdx.x;
    int base = blockIdx.x * SCAN_CHUNK + t * 4;
    int v0 = (base + 0 < n) ? deg[base + 0] : 0;
    int v1 = (base + 1 < n) ? deg[base + 1] : 0;
    int v2 = (base + 2 < n) ? deg[base + 2] : 0;
    int v3 = (base + 3 < n) ? deg[base + 3] : 0;
    int s = v0 + v1 + v2 + v3;
    int lane = t & 63, wave = t >> 6;
    int inc = s;
    for (int off = 1; off < 64; off <<= 1) {
        int u = __shfl_up(inc, off);
        if (lane >= off) inc += u;
    }
    if (lane == 63) wsum[wave] = inc;
    __syncthreads();
    int woff = 0;
    for (int w = 0; w < wave; ++w) woff += wsum[w];
    int ex = woff + inc - s;
    if (base + 0 < n) loc[base + 0] = ex;
    if (base + 1 < n) loc[base + 1] = ex + v0;
    if (base + 2 < n) loc[base + 2] = ex + v0 + v1;
    if (base + 3 < n) loc[base + 3] = ex + v0 + v1 + v2;
    if (t == 255) partial[blockIdx.x] = woff + inc;
}

__global__ __launch_bounds__(1024) void scan2_kernel(int* __restrict__ partial, int nchunk)
{
    __shared__ int sd[1024];
    int t = threadIdx.x;
    if (t < nchunk) sd[t] = partial[t];
    __syncthreads();
    if (t == 0) {
        int run = 0;
        for (int i = 0; i < nchunk; ++i) { int v = sd[i]; sd[i] = run; run += v; }
    }
    __syncthreads();
    if (t < nchunk) partial[t] = sd[t];
}

__global__ __launch_bounds__(256) void scan3_kernel(
    int* __restrict__ rowptr, const int* __restrict__ partial,
    int* __restrict__ cursor, int n, int Etot)
{
    int i = blockIdx.x * 256 + threadIdx.x;
    if (i == 0) rowptr[n] = Etot;
    if (i >= n) return;
    int v = rowptr[i] + partial[i >> 10];
    rowptr[i] = v;
    cursor[i] = v;
}

// ---------------- heterogeneous: gemm1 (blocks < nGemm) ∥ fill (rest) ----------------
// gemm1: xr1[i] = x[i]@Wrel1^T (bf16); io[i] = x[i]@Wroot1^T + b1 (f32)   [r10 verbatim]
// fill:  pairs[cursor[dst]++] = (src, w)                                   [r10 verbatim]
// Disjoint outputs; no inter-block dependency.
#define GW 8   // waves/block (512 threads)
#define GR 4   // rows/wave
__global__ __launch_bounds__(512) void fill_gemm1_kernel(
    const int* __restrict__ ei, const float* __restrict__ ew,
    int* __restrict__ cursor, uint64_t* __restrict__ pairs, int E_,
    const float* __restrict__ x,
    const float* __restrict__ Wrel, const float* __restrict__ brel,
    const float* __restrict__ Wroot,
    u16* __restrict__ xr, float* __restrict__ io, int Nn, int nGemm)
{
    __shared__ float WrelT[D][D + 1];   // padded: staging writes AND reads conflict-free
    __shared__ float WrootT[D][D + 1];
    __shared__ float bias[D];
    __shared__ float rowX[GW][GR][D];

    int tid = threadIdx.x;

    if ((int)blockIdx.x >= nGemm) {
        // ---- fill path (memory-stall bound; r10-fastest store variant) ----
        int e = ((int)blockIdx.x - nGemm) * 512 + tid;
        if (e >= E_) return;
        int src = ei[e];
        int dst = ei[E_ + e];
        int p = atomicAdd(&cursor[dst], 1);
        uint64_t packed = (uint64_t)(u32)src | ((uint64_t)__float_as_uint(ew[e]) << 32);
        __hip_atomic_store(&pairs[p], packed, __ATOMIC_RELAXED, __HIP_MEMORY_SCOPE_SYSTEM);
        return;
    }

    // ---- gemm1 path (r10 verbatim) ----
    for (int i = tid; i < D * D; i += 512) {
        int d = i >> 6, k = i & 63;
        WrelT [k][d] = Wrel [i];
        WrootT[k][d] = Wroot[i];
    }
    if (tid < D) bias[tid] = brel[tid];
    __syncthreads();

    int wave = tid >> 6, lane = tid & 63;
    int base = ((int)blockIdx.x * GW + wave) * GR;
    if (base >= Nn) return;             // wave-uniform, after barrier
    int nr = min(GR, Nn - base);

    for (int r = 0; r < nr; ++r)
        rowX[wave][r][lane] = x[(size_t)(base + r) * D + lane];
    // same-wave LDS write->read (proven)

    float aR[GR] = {0.f, 0.f, 0.f, 0.f};
    float aC[GR] = {0.f, 0.f, 0.f, 0.f};
#pragma unroll
    for (int k4 = 0; k4 < 16; ++k4) {
        float4 xv[GR];
#pragma unroll
        for (int r = 0; r < GR; ++r)
            xv[r] = *reinterpret_cast<const float4*>(&rowX[wave][r][k4 * 4]); // broadcast b128
#pragma unroll
        for (int kk = 0; kk < 4; ++kk) {
            float wr = WrelT [k4 * 4 + kk][lane];
            float wc = WrootT[k4 * 4 + kk][lane];
#pragma unroll
            for (int r = 0; r < GR; ++r) {
                float xk = (kk == 0) ? xv[r].x : (kk == 1) ? xv[r].y
                         : (kk == 2) ? xv[r].z : xv[r].w;
                aR[r] = fmaf(xk, wr, aR[r]);
                aC[r] = fmaf(xk, wc, aC[r]);
            }
        }
    }
    for (int r = 0; r < nr; ++r) {
        size_t o = (size_t)(base + r) * D + lane;
        xr[o] = f2bf(aR[r]);
        io[o] = aC[r] + bias[lane];
    }
}

// ---------------- gather1_fused: ILP-8 gather + gemm2 epilogue (1 row/wave) ----------------
// h = relu(sum_j w_j*xr1[src_j] + io[i]);  xr2[i] = h@Wrel2^T (bf16);
// io[i] = h@Wroot2^T + b2.  Epilogue correctness proven r8; schedule fixed.
__global__ __launch_bounds__(512) void gather1_fused(
    const u16* __restrict__ xr1, const uint64_t* __restrict__ pairs,
    const int* __restrict__ rowptr,
    const float* __restrict__ Wrel, const float* __restrict__ brel,
    const float* __restrict__ Wroot,
    u16* __restrict__ xr2, float* __restrict__ io, int Nn)
{
    __shared__ float WrelT[D][D + 1];
    __shared__ float WrootT[D][D + 1];
    __shared__ float bias[D];
    __shared__ float rowH[8][D];

    int tid = threadIdx.x;
    for (int i2 = tid; i2 < D * D; i2 += 512) {
        int d = i2 >> 6, k = i2 & 63;
        WrelT [k][d] = Wrel [i2];
        WrootT[k][d] = Wroot[i2];
    }
    if (tid < D) bias[tid] = brel[tid];
    __syncthreads();

    int wave = tid >> 6, lane = tid & 63;
    int i = (int)blockIdx.x * 8 + wave;
    if (i >= Nn) return;                       // wave-uniform, after barrier

    int beg = rowptr[i], end = rowptr[i + 1];
    float acc = 0.f;
    for (int b = beg; b < end; b += 64) {
        int cnt = min(64, end - b);
        // lanes >= cnt carry (src=0, w=0): padded edges read row 0, add 0
        uint64_t pv = (lane < cnt) ? __builtin_nontemporal_load(&pairs[b + lane])
                                   : (uint64_t)0;
        int   ps = (int)(u32)pv;
        float wv = __uint_as_float((u32)(pv >> 32));
        for (int j = 0; j < cnt; j += 8) {     // 8 independent gathers in flight
            int   s0 = __shfl(ps, j + 0), s1 = __shfl(ps, j + 1);
            int   s2 = __shfl(ps, j + 2), s3 = __shfl(ps, j + 3);
            int   s4 = __shfl(ps, j + 4), s5 = __shfl(ps, j + 5);
            int   s6 = __shfl(ps, j + 6), s7 = __shfl(ps, j + 7);
            float w0 = __shfl(wv, j + 0), w1 = __shfl(wv, j + 1);
            float w2 = __shfl(wv, j + 2), w3 = __shfl(wv, j + 3);
            float w4 = __shfl(wv, j + 4), w5 = __shfl(wv, j + 5);
            float w6 = __shfl(wv, j + 6), w7 = __shfl(wv, j + 7);
            float v0 = bf2f(xr1[(size_t)s0 * D + lane]);
            float v1 = bf2f(xr1[(size_t)s1 * D + lane]);
            float v2 = bf2f(xr1[(size_t)s2 * D + lane]);
            float v3 = bf2f(xr1[(size_t)s3 * D + lane]);
            float v4 = bf2f(xr1[(size_t)s4 * D + lane]);
            float v5 = bf2f(xr1[(size_t)s5 * D + lane]);
            float v6 = bf2f(xr1[(size_t)s6 * D + lane]);
            float v7 = bf2f(xr1[(size_t)s7 * D + lane]);
            acc = fmaf(v0, w0, acc); acc = fmaf(v1, w1, acc);
            acc = fmaf(v2, w2, acc); acc = fmaf(v3, w3, acc);
            acc = fmaf(v4, w4, acc); acc = fmaf(v5, w5, acc);
            acc = fmaf(v6, w6, acc); acc = fmaf(v7, w7, acc);
        }
    }

    size_t o = (size_t)i * D + lane;
    float h = fmaxf(acc + io[o], 0.f);         // ReLU

    rowH[wave][lane] = h;
    // same-wave LDS write->read (proven)

    const float4* rH4 = reinterpret_cast<const float4*>(rowH[wave]);
    float aR = 0.f;
    float aC = bias[lane];
#pragma unroll
    for (int k4 = 0; k4 < 16; ++k4) {
        float4 hv = rH4[k4];                   // broadcast b128
        int k = k4 * 4;
        aR = fmaf(hv.x, WrelT [k + 0][lane], aR);
        aR = fmaf(hv.y, WrelT [k + 1][lane], aR);
        aR = fmaf(hv.z, WrelT [k + 2][lane], aR);
        aR = fmaf(hv.w, WrelT [k + 3][lane], aR);
        aC = fmaf(hv.x, WrootT[k + 0][lane], aC);
        aC = fmaf(hv.y, WrootT[k + 1][lane], aC);
        aC = fmaf(hv.z, WrootT[k + 2][lane], aC);
        aC = fmaf(hv.w, WrootT[k + 3][lane], aC);
    }
    xr2[o] = f2bf(aR);
    io[o]  = aC;        // row i fully owned by this wave
}

// ---------------- gather2: ILP-8, bf16 rows (r10 verbatim) ----------------
#define AW 8
__global__ __launch_bounds__(512) void gather2_kernel(
    const u16* __restrict__ xr, const uint64_t* __restrict__ pairs,
    const int* __restrict__ rowptr, float* __restrict__ io, int Nn)
{
    int tid  = threadIdx.x;
    int wave = tid >> 6, lane = tid & 63;
    int i = blockIdx.x * AW + wave;
    if (i >= Nn) return;                       // wave-uniform

    int beg = rowptr[i], end = rowptr[i + 1];
    float acc = 0.f;
    for (int b = beg; b < end; b += 64) {
        int cnt = min(64, end - b);
        uint64_t pv = (lane < cnt) ? __builtin_nontemporal_load(&pairs[b + lane])
                                   : (uint64_t)0;
        int   ps = (int)(u32)pv;
        float wv = __uint_as_float((u32)(pv >> 32));
        for (int j = 0; j < cnt; j += 8) {
            int   s0 = __shfl(ps, j + 0), s1 = __shfl(ps, j + 1);
            int   s2 = __shfl(ps, j + 2), s3 = __shfl(ps, j + 3);
            int   s4 = __shfl(ps, j + 4), s5 = __shfl(ps, j + 5);
            int   s6 = __shfl(ps, j + 6), s7 = __shfl(ps, j + 7);
            float w0 = __shfl(wv, j + 0), w1 = __shfl(wv, j + 1);
            float w2 = __shfl(wv, j + 2), w3 = __shfl(wv, j + 3);
            float w4 = __shfl(wv, j + 4), w5 = __shfl(wv, j + 5);
            float w6 = __shfl(wv, j + 6), w7 = __shfl(wv, j + 7);
            float v0 = bf2f(xr[(size_t)s0 * D + lane]);
            float v1 = bf2f(xr[(size_t)s1 * D + lane]);
            float v2 = bf2f(xr[(size_t)s2 * D + lane]);
            float v3 = bf2f(xr[(size_t)s3 * D + lane]);
            float v4 = bf2f(xr[(size_t)s4 * D + lane]);
            float v5 = bf2f(xr[(size_t)s5 * D + lane]);
            float v6 = bf2f(xr[(size_t)s6 * D + lane]);
            float v7 = bf2f(xr[(size_t)s7 * D + lane]);
            acc = fmaf(v0, w0, acc); acc = fmaf(v1, w1, acc);
            acc = fmaf(v2, w2, acc); acc = fmaf(v3, w3, acc);
            acc = fmaf(v4, w4, acc); acc = fmaf(v5, w5, acc);
            acc = fmaf(v6, w6, acc); acc = fmaf(v7, w7, acc);
        }
    }
    size_t o = (size_t)i * D + lane;
    io[o] = acc + io[o];
}

extern "C" void kernel_launch(void* const* d_in, const int* in_sizes, int n_in,
                              void* d_out, int out_size, void* d_ws, size_t ws_size,
                              hipStream_t stream)
{
    const float* x      = (const float*)d_in[0];
    const int*   ei     = (const int*)  d_in[1];
    const float* ew     = (const float*)d_in[2];
    const float* Wrel1  = (const float*)d_in[3];
    const float* brel1  = (const float*)d_in[4];
    const float* Wroot1 = (const float*)d_in[5];
    const float* Wrel2  = (const float*)d_in[6];
    const float* brel2  = (const float*)d_in[7];
    const float* Wroot2 = (const float*)d_in[8];
    float* out = (float*)d_out;

    const int E_ = in_sizes[2];          // 1600000
    const int Nn = in_sizes[0] / D;      // 100000

    // workspace layout — r8-proven 39.2 MB footprint
    char* w = (char*)d_ws;
    size_t off = 0;
    u16*  xr1    = (u16*)(w + off); off += (size_t)Nn * D * sizeof(u16);   // 12.8 MB
    u16*  xr2    = (u16*)(w + off); off += (size_t)Nn * D * sizeof(u16);   // 12.8 MB
    int*  rowptr = (int*)(w + off); off += (size_t)(Nn + 1) * sizeof(int);
    int*  cursor = (int*)(w + off); off += (size_t)Nn * sizeof(int);
    int*  partial= (int*)(w + off); off += 1024 * sizeof(int);
    off = (off + 15) & ~(size_t)15;
    uint64_t* pairs = (uint64_t*)(w + off);                                // 12.8 MB

    const int nchunk  = (Nn + SCAN_CHUNK - 1) / SCAN_CHUNK;
    const int eBlocks = (E_ + 255) / 256;
    const int nGemm   = (Nn + GW * GR - 1) / (GW * GR);    // 3125
    const int nFill   = (E_ + 511) / 512;                  // 3125
    const int g1Blocks = (Nn + 7) / 8;                     // 12500
    const int g2Blocks = (Nn + AW - 1) / AW;               // 12500

    // ---- CSR front ----
    (void)hipMemsetAsync(cursor, 0, (size_t)Nn * sizeof(int), stream);
    hist_kernel<<<eBlocks, 256, 0, stream>>>(ei, cursor, E_);
    scan1_kernel<<<nchunk, 256, 0, stream>>>(cursor, rowptr, partial, Nn);
    scan2_kernel<<<1, 1024, 0, stream>>>(partial, nchunk);
    scan3_kernel<<<(Nn + 255) / 256, 256, 0, stream>>>(rowptr, partial, cursor, Nn, E_);

    // ---- fill ∥ gemm1 (heterogeneous; disjoint outputs) ----
    fill_gemm1_kernel<<<nGemm + nFill, 512, 0, stream>>>(
        ei, ew, cursor, pairs, E_, x, Wrel1, brel1, Wroot1, xr1, out, Nn, nGemm);

    // ---- gather1 + relu + gemm2 (fused epilogue) ----
    gather1_fused<<<g1Blocks, 512, 0, stream>>>(xr1, pairs, rowptr,
                                                Wrel2, brel2, Wroot2, xr2, out, Nn);

    // ---- gather2 (final) ----
    gather2_kernel<<<g2Blocks, 512, 0, stream>>>(xr2, pairs, rowptr, out, Nn);
}

// Round 14
// 355.437 us; speedup vs baseline: 1.0698x; 1.0698x over previous
//
#include <hip/hip_runtime.h>
#include <hip/hip_bf16.h>
#include <stdint.h>

// GraphConv x2 — round 14: exact r10 structure (best: 363us), gather inner
// loop restructured to scalar-uniform loads:
//   readfirstlane(beg/end) -> pairs[b+jj] is a uniform s_load_dwordx2 (src,w
//   in SGPRs) -> row load is global_load_ushort with SGPR base + lane offset.
//   Replaces 2 ds_bpermute per edge; tail via scalar selects + 8-entry pad.
//   CSR by dst (proven). Per layer:
//     gemm:   xr = x @ Wrel^T (bf16);  io = x @ Wroot^T + b  (io==d_out, f32)
//     gather: io[i] = [relu]( sum_j w_j * xr[src_j] + io[i] )  in place
// N=100000, E=1600000, D=64

#define D 64
#define SCAN_CHUNK 1024

typedef unsigned int   u32;
typedef unsigned short u16;

__device__ __forceinline__ float bf2f(u16 v) {
    return __uint_as_float(((u32)v) << 16);
}
__device__ __forceinline__ u16 f2bf(float f) {
    u32 u = __float_as_uint(f);
    u32 r = (u + 0x7fffu + ((u >> 16) & 1u)) >> 16;   // round-to-nearest-even
    return (u16)r;
}

// ---------------- CSR build (r10 verbatim, proven) ----------------
__global__ __launch_bounds__(256) void hist_kernel(
    const int* __restrict__ ei, int* __restrict__ deg, int E_)
{
    int e = blockIdx.x * 256 + threadIdx.x;
    if (e >= E_) return;
    atomicAdd(&deg[ei[E_ + e]], 1);
}

__global__ __launch_bounds__(256) void scan1_kernel(
    const int* __restrict__ deg, int* __restrict__ loc, int* __restrict__ partial, int n)
{
    __shared__ int wsum[4];
    int t = threadIdx.x;
    int base = blockIdx.x * SCAN_CHUNK + t * 4;
    int v0 = (base + 0 < n) ? deg[base + 0] : 0;
    int v1 = (base + 1 < n) ? deg[base + 1] : 0;
    int v2 = (base + 2 < n) ? deg[base + 2] : 0;
    int v3 = (base + 3 < n) ? deg[base + 3] : 0;
    int s = v0 + v1 + v2 + v3;
    int lane = t & 63, wave = t >> 6;
    int inc = s;
    for (int off = 1; off < 64; off <<= 1) {
        int u = __shfl_up(inc, off);
        if (lane >= off) inc += u;
    }
    if (lane == 63) wsum[wave] = inc;
    __syncthreads();
    int woff = 0;
    for (int w = 0; w < wave; ++w) woff += wsum[w];
    int ex = woff + inc - s;
    if (base + 0 < n) loc[base + 0] = ex;
    if (base + 1 < n) loc[base + 1] = ex + v0;
    if (base + 2 < n) loc[base + 2] = ex + v0 + v1;
    if (base + 3 < n) loc[base + 3] = ex + v0 + v1 + v2;
    if (t == 255) partial[blockIdx.x] = woff + inc;
}

__global__ __launch_bounds__(1024) void scan2_kernel(int* __restrict__ partial, int nchunk)
{
    __shared__ int sd[1024];
    int t = threadIdx.x;
    if (t < nchunk) sd[t] = partial[t];
    __syncthreads();
    if (t == 0) {
        int run = 0;
        for (int i = 0; i < nchunk; ++i) { int v = sd[i]; sd[i] = run; run += v; }
    }
    __syncthreads();
    if (t < nchunk) partial[t] = sd[t];
}

__global__ __launch_bounds__(256) void scan3_kernel(
    int* __restrict__ rowptr, const int* __restrict__ partial,
    int* __restrict__ cursor, int n, int Etot)
{
    int i = blockIdx.x * 256 + threadIdx.x;
    if (i == 0) rowptr[n] = Etot;
    if (i >= n) return;
    int v = rowptr[i] + partial[i >> 10];
    rowptr[i] = v;
    cursor[i] = v;
}

__global__ __launch_bounds__(256) void fill_kernel(
    const int* __restrict__ ei, const float* __restrict__ ew,
    int* __restrict__ cursor, uint64_t* __restrict__ pairs, int E_)
{
    int e = blockIdx.x * 256 + threadIdx.x;
    if (e >= E_) return;
    int src = ei[e];
    int dst = ei[E_ + e];
    int p = atomicAdd(&cursor[dst], 1);
    // low word = src, high word = weight bits
    uint64_t packed = (uint64_t)(u32)src | ((uint64_t)__float_as_uint(ew[e]) << 32);
    // fastest measured variant (r10: 97us vs plain 120 / nt 125 / atomicExch 146)
    __hip_atomic_store(&pairs[p], packed, __ATOMIC_RELAXED, __HIP_MEMORY_SCOPE_SYSTEM);
}

// ---------------- pre-transform GEMM (r10 verbatim, proven) ----------------
// xr[i] = xin[i] @ Wrel^T (bf16);  io[i] = xin[i] @ Wroot^T + b (f32).
// xin MAY ALIAS io (layer 2) — each row read before same-row write, same wave.
#define GW 8   // waves/block (512 threads)
#define GR 4   // rows/wave
__global__ __launch_bounds__(512) void gemm_kernel(
    const float* xin,
    const float* __restrict__ Wrel, const float* __restrict__ brel,
    const float* __restrict__ Wroot,
    u16* __restrict__ xr, float* io, int Nn)
{
    __shared__ float WrelT[D][D + 1];   // padded: staging writes AND reads conflict-free
    __shared__ float WrootT[D][D + 1];
    __shared__ float bias[D];
    __shared__ float rowX[GW][GR][D];

    int tid = threadIdx.x;
    for (int i = tid; i < D * D; i += 512) {
        int d = i >> 6, k = i & 63;
        WrelT [k][d] = Wrel [i];
        WrootT[k][d] = Wroot[i];
    }
    if (tid < D) bias[tid] = brel[tid];
    __syncthreads();

    int wave = tid >> 6, lane = tid & 63;

    int base = (blockIdx.x * GW + wave) * GR;
    if (base >= Nn) return;             // wave-uniform, after barrier
    int nr = min(GR, Nn - base);

    for (int r = 0; r < nr; ++r)
        rowX[wave][r][lane] = xin[(size_t)(base + r) * D + lane];
    // same-wave LDS write->read (proven)

    float aR[GR] = {0.f, 0.f, 0.f, 0.f};
    float aC[GR] = {0.f, 0.f, 0.f, 0.f};
#pragma unroll
    for (int k4 = 0; k4 < 16; ++k4) {
        float4 xv[GR];
#pragma unroll
        for (int r = 0; r < GR; ++r)
            xv[r] = *reinterpret_cast<const float4*>(&rowX[wave][r][k4 * 4]); // broadcast b128
#pragma unroll
        for (int kk = 0; kk < 4; ++kk) {
            float wr = WrelT [k4 * 4 + kk][lane];
            float wc = WrootT[k4 * 4 + kk][lane];
#pragma unroll
            for (int r = 0; r < GR; ++r) {
                float xk = (kk == 0) ? xv[r].x : (kk == 1) ? xv[r].y
                         : (kk == 2) ? xv[r].z : xv[r].w;
                aR[r] = fmaf(xk, wr, aR[r]);
                aC[r] = fmaf(xk, wc, aC[r]);
            }
        }
    }
    for (int r = 0; r < nr; ++r) {
        size_t o = (size_t)(base + r) * D + lane;
        xr[o] = f2bf(aR[r]);
        io[o] = aC[r] + bias[lane];
    }
}

// ---------------- gather: scalar-uniform pair loads, 8-deep MLP ----------------
#define AW 8
template <bool RELU>
__global__ __launch_bounds__(512) void gather_kernel(
    const u16* __restrict__ xr, const uint64_t* __restrict__ pairs,
    const int* __restrict__ rowptr, float* __restrict__ io, int Nn)
{
    int tid  = threadIdx.x;
    int wave = tid >> 6, lane = tid & 63;
    int i = blockIdx.x * AW + wave;
    if (i >= Nn) return;                       // wave-uniform

    // force SGPR: pairs[...] addresses become provably uniform -> s_load
    int beg = __builtin_amdgcn_readfirstlane(rowptr[i]);
    int end = __builtin_amdgcn_readfirstlane(rowptr[i + 1]);

    float acc = 0.f;
    for (int b = beg; b < end; b += 8) {
#pragma unroll
        for (int jj = 0; jj < 8; ++jj) {
            // uniform 8B load (s_load_dwordx2); pairs has an 8-entry pad past E
            uint64_t p = pairs[b + jj];
            int   s  = (int)(u32)p;
            float wr = __uint_as_float((u32)(p >> 32));
            bool valid = (b + jj) < end;       // scalar select on tail
            s  = valid ? s  : 0;
            float w = valid ? wr : 0.f;
            // SGPR base + lane offset: global_load_ushort
            float v = bf2f(xr[(size_t)s * D + lane]);
            acc = fmaf(v, w, acc);
        }
    }
    size_t o = (size_t)i * D + lane;
    float v = acc + io[o];
    io[o] = RELU ? fmaxf(v, 0.f) : v;
}

extern "C" void kernel_launch(void* const* d_in, const int* in_sizes, int n_in,
                              void* d_out, int out_size, void* d_ws, size_t ws_size,
                              hipStream_t stream)
{
    const float* x      = (const float*)d_in[0];
    const int*   ei     = (const int*)  d_in[1];
    const float* ew     = (const float*)d_in[2];
    const float* Wrel1  = (const float*)d_in[3];
    const float* brel1  = (const float*)d_in[4];
    const float* Wroot1 = (const float*)d_in[5];
    const float* Wrel2  = (const float*)d_in[6];
    const float* brel2  = (const float*)d_in[7];
    const float* Wroot2 = (const float*)d_in[8];
    float* out = (float*)d_out;

    const int E_ = in_sizes[2];          // 1600000
    const int Nn = in_sizes[0] / D;      // 100000

    // workspace layout — ~26.4 MB total (+64B pair pad; well under proven fit)
    char* w = (char*)d_ws;
    size_t off = 0;
    u16*  xr     = (u16*)(w + off); off += (size_t)Nn * D * sizeof(u16);   // 12.8 MB
    int*  rowptr = (int*)(w + off); off += (size_t)(Nn + 1) * sizeof(int);
    int*  cursor = (int*)(w + off); off += (size_t)Nn * sizeof(int);
    int*  partial= (int*)(w + off); off += 1024 * sizeof(int);
    off = (off + 15) & ~(size_t)15;
    uint64_t* pairs = (uint64_t*)(w + off);                                // 12.8 MB + 64B pad

    const int nchunk  = (Nn + SCAN_CHUNK - 1) / SCAN_CHUNK;
    const int eBlocks = (E_ + 255) / 256;
    const int gemmBlocks   = (Nn + GW * GR - 1) / (GW * GR);
    const int gatherBlocks = (Nn + AW - 1) / AW;

    // ---- CSR build (reused by both layers) ----
    (void)hipMemsetAsync(cursor, 0, (size_t)Nn * sizeof(int), stream);
    hist_kernel<<<eBlocks, 256, 0, stream>>>(ei, cursor, E_);
    scan1_kernel<<<nchunk, 256, 0, stream>>>(cursor, rowptr, partial, Nn);
    scan2_kernel<<<1, 1024, 0, stream>>>(partial, nchunk);
    scan3_kernel<<<(Nn + 255) / 256, 256, 0, stream>>>(rowptr, partial, cursor, Nn, E_);
    fill_kernel<<<eBlocks, 256, 0, stream>>>(ei, ew, cursor, pairs, E_);

    // ---- layer 1: out = x@Wroot1^T+b1;  out = relu(gather(xr1) + out) ----
    gemm_kernel<<<gemmBlocks, 512, 0, stream>>>(x, Wrel1, brel1, Wroot1, xr, out, Nn);
    gather_kernel<true><<<gatherBlocks, 512, 0, stream>>>(xr, pairs, rowptr, out, Nn);

    // ---- layer 2: xr2 = h@Wrel2^T; out = h@Wroot2^T+b2 (in place);  out += gather(xr2) ----
    gemm_kernel<<<gemmBlocks, 512, 0, stream>>>(out, Wrel2, brel2, Wroot2, xr, out, Nn);
    gather_kernel<false><<<gatherBlocks, 512, 0, stream>>>(xr, pairs, rowptr, out, Nn);
}

// Round 15
// 348.862 us; speedup vs baseline: 1.0899x; 1.0188x over previous
//
#include <hip/hip_runtime.h>
#include <hip/hip_bf16.h>
#include <stdint.h>

// GraphConv x2 — round 15: r14 base (355us best) + ONE change:
//   gemm2 fused into gather1 epilogue (1 row/wave, full grid — the config
//   r13 measured as ~free; r13's regression was the fill∥gemm1 half, dropped).
//   Pipeline: memset,hist,scan1-3,fill -> gemm1 -> gather1_fused -> gather2
//     gemm1:         xr1 = x@Wrel1^T (bf16);  d_out = x@Wroot1^T + b1 (f32)
//     gather1_fused: h = relu(scalar-gather(xr1) + d_out[i])  [registers]
//                    xr2[i] = h@Wrel2^T (bf16);  d_out[i] = h@Wroot2^T + b2
//     gather2:       d_out[i] += scalar-gather(xr2)
// N=100000, E=1600000, D=64

#define D 64
#define SCAN_CHUNK 1024

typedef unsigned int   u32;
typedef unsigned short u16;

__device__ __forceinline__ float bf2f(u16 v) {
    return __uint_as_float(((u32)v) << 16);
}
__device__ __forceinline__ u16 f2bf(float f) {
    u32 u = __float_as_uint(f);
    u32 r = (u + 0x7fffu + ((u >> 16) & 1u)) >> 16;   // round-to-nearest-even
    return (u16)r;
}

// ---------------- CSR build (r14 verbatim, proven) ----------------
__global__ __launch_bounds__(256) void hist_kernel(
    const int* __restrict__ ei, int* __restrict__ deg, int E_)
{
    int e = blockIdx.x * 256 + threadIdx.x;
    if (e >= E_) return;
    atomicAdd(&deg[ei[E_ + e]], 1);
}

__global__ __launch_bounds__(256) void scan1_kernel(
    const int* __restrict__ deg, int* __restrict__ loc, int* __restrict__ partial, int n)
{
    __shared__ int wsum[4];
    int t = threadIdx.x;
    int base = blockIdx.x * SCAN_CHUNK + t * 4;
    int v0 = (base + 0 < n) ? deg[base + 0] : 0;
    int v1 = (base + 1 < n) ? deg[base + 1] : 0;
    int v2 = (base + 2 < n) ? deg[base + 2] : 0;
    int v3 = (base + 3 < n) ? deg[base + 3] : 0;
    int s = v0 + v1 + v2 + v3;
    int lane = t & 63, wave = t >> 6;
    int inc = s;
    for (int off = 1; off < 64; off <<= 1) {
        int u = __shfl_up(inc, off);
        if (lane >= off) inc += u;
    }
    if (lane == 63) wsum[wave] = inc;
    __syncthreads();
    int woff = 0;
    for (int w = 0; w < wave; ++w) woff += wsum[w];
    int ex = woff + inc - s;
    if (base + 0 < n) loc[base + 0] = ex;
    if (base + 1 < n) loc[base + 1] = ex + v0;
    if (base + 2 < n) loc[base + 2] = ex + v0 + v1;
    if (base + 3 < n) loc[base + 3] = ex + v0 + v1 + v2;
    if (t == 255) partial[blockIdx.x] = woff + inc;
}

__global__ __launch_bounds__(1024) void scan2_kernel(int* __restrict__ partial, int nchunk)
{
    __shared__ int sd[1024];
    int t = threadIdx.x;
    if (t < nchunk) sd[t] = partial[t];
    __syncthreads();
    if (t == 0) {
        int run = 0;
        for (int i = 0; i < nchunk; ++i) { int v = sd[i]; sd[i] = run; run += v; }
    }
    __syncthreads();
    if (t < nchunk) partial[t] = sd[t];
}

__global__ __launch_bounds__(256) void scan3_kernel(
    int* __restrict__ rowptr, const int* __restrict__ partial,
    int* __restrict__ cursor, int n, int Etot)
{
    int i = blockIdx.x * 256 + threadIdx.x;
    if (i == 0) rowptr[n] = Etot;
    if (i >= n) return;
    int v = rowptr[i] + partial[i >> 10];
    rowptr[i] = v;
    cursor[i] = v;
}

__global__ __launch_bounds__(256) void fill_kernel(
    const int* __restrict__ ei, const float* __restrict__ ew,
    int* __restrict__ cursor, uint64_t* __restrict__ pairs, int E_)
{
    int e = blockIdx.x * 256 + threadIdx.x;
    if (e >= E_) return;
    int src = ei[e];
    int dst = ei[E_ + e];
    int p = atomicAdd(&cursor[dst], 1);
    uint64_t packed = (uint64_t)(u32)src | ((uint64_t)__float_as_uint(ew[e]) << 32);
    // fastest measured store variant (r10: 97us vs plain 120 / nt 125 / atomicExch 146)
    __hip_atomic_store(&pairs[p], packed, __ATOMIC_RELAXED, __HIP_MEMORY_SCOPE_SYSTEM);
}

// ---------------- gemm1 (r14 verbatim, proven) ----------------
#define GW 8   // waves/block (512 threads)
#define GR 4   // rows/wave
__global__ __launch_bounds__(512) void gemm_kernel(
    const float* xin,
    const float* __restrict__ Wrel, const float* __restrict__ brel,
    const float* __restrict__ Wroot,
    u16* __restrict__ xr, float* io, int Nn)
{
    __shared__ float WrelT[D][D + 1];   // padded: staging writes AND reads conflict-free
    __shared__ float WrootT[D][D + 1];
    __shared__ float bias[D];
    __shared__ float rowX[GW][GR][D];

    int tid = threadIdx.x;
    for (int i = tid; i < D * D; i += 512) {
        int d = i >> 6, k = i & 63;
        WrelT [k][d] = Wrel [i];
        WrootT[k][d] = Wroot[i];
    }
    if (tid < D) bias[tid] = brel[tid];
    __syncthreads();

    int wave = tid >> 6, lane = tid & 63;

    int base = (blockIdx.x * GW + wave) * GR;
    if (base >= Nn) return;             // wave-uniform, after barrier
    int nr = min(GR, Nn - base);

    for (int r = 0; r < nr; ++r)
        rowX[wave][r][lane] = xin[(size_t)(base + r) * D + lane];
    // same-wave LDS write->read (proven)

    float aR[GR] = {0.f, 0.f, 0.f, 0.f};
    float aC[GR] = {0.f, 0.f, 0.f, 0.f};
#pragma unroll
    for (int k4 = 0; k4 < 16; ++k4) {
        float4 xv[GR];
#pragma unroll
        for (int r = 0; r < GR; ++r)
            xv[r] = *reinterpret_cast<const float4*>(&rowX[wave][r][k4 * 4]); // broadcast b128
#pragma unroll
        for (int kk = 0; kk < 4; ++kk) {
            float wr = WrelT [k4 * 4 + kk][lane];
            float wc = WrootT[k4 * 4 + kk][lane];
#pragma unroll
            for (int r = 0; r < GR; ++r) {
                float xk = (kk == 0) ? xv[r].x : (kk == 1) ? xv[r].y
                         : (kk == 2) ? xv[r].z : xv[r].w;
                aR[r] = fmaf(xk, wr, aR[r]);
                aC[r] = fmaf(xk, wc, aC[r]);
            }
        }
    }
    for (int r = 0; r < nr; ++r) {
        size_t o = (size_t)(base + r) * D + lane;
        xr[o] = f2bf(aR[r]);
        io[o] = aC[r] + bias[lane];
    }
}

// ---------------- gather1_fused: scalar-uniform gather + gemm2 epilogue ----------------
// 1 row/wave, full grid (r13-measured-cheap config, r14 gather loop).
__global__ __launch_bounds__(512) void gather1_fused(
    const u16* __restrict__ xr1, const uint64_t* __restrict__ pairs,
    const int* __restrict__ rowptr,
    const float* __restrict__ Wrel, const float* __restrict__ brel,
    const float* __restrict__ Wroot,
    u16* __restrict__ xr2, float* __restrict__ io, int Nn)
{
    __shared__ float WrelT[D][D + 1];
    __shared__ float WrootT[D][D + 1];
    __shared__ float bias[D];
    __shared__ float rowH[GW][D];

    int tid = threadIdx.x;
    for (int i2 = tid; i2 < D * D; i2 += 512) {
        int d = i2 >> 6, k = i2 & 63;
        WrelT [k][d] = Wrel [i2];
        WrootT[k][d] = Wroot[i2];
    }
    if (tid < D) bias[tid] = brel[tid];
    __syncthreads();

    int wave = tid >> 6, lane = tid & 63;
    int i = (int)blockIdx.x * GW + wave;
    if (i >= Nn) return;                       // wave-uniform, after barrier

    // force SGPR: pairs addresses provably uniform -> s_load
    int beg = __builtin_amdgcn_readfirstlane(rowptr[i]);
    int end = __builtin_amdgcn_readfirstlane(rowptr[i + 1]);

    float acc = 0.f;
    for (int b = beg; b < end; b += 8) {
#pragma unroll
        for (int jj = 0; jj < 8; ++jj) {
            uint64_t p = pairs[b + jj];        // uniform s_load_dwordx2 (pad past E)
            int   s  = (int)(u32)p;
            float wr = __uint_as_float((u32)(p >> 32));
            bool valid = (b + jj) < end;       // scalar tail select
            s = valid ? s : 0;
            float w = valid ? wr : 0.f;
            float v = bf2f(xr1[(size_t)s * D + lane]);  // SGPR base + lane offset
            acc = fmaf(v, w, acc);
        }
    }

    size_t o = (size_t)i * D + lane;
    float h = fmaxf(acc + io[o], 0.f);         // ReLU

    rowH[wave][lane] = h;
    // same-wave LDS write->read (proven)

    const float4* rH4 = reinterpret_cast<const float4*>(rowH[wave]);
    float aR = 0.f;
    float aC = bias[lane];
#pragma unroll
    for (int k4 = 0; k4 < 16; ++k4) {
        float4 hv = rH4[k4];                   // broadcast b128
        int k = k4 * 4;
        aR = fmaf(hv.x, WrelT [k + 0][lane], aR);
        aR = fmaf(hv.y, WrelT [k + 1][lane], aR);
        aR = fmaf(hv.z, WrelT [k + 2][lane], aR);
        aR = fmaf(hv.w, WrelT [k + 3][lane], aR);
        aC = fmaf(hv.x, WrootT[k + 0][lane], aC);
        aC = fmaf(hv.y, WrootT[k + 1][lane], aC);
        aC = fmaf(hv.z, WrootT[k + 2][lane], aC);
        aC = fmaf(hv.w, WrootT[k + 3][lane], aC);
    }
    xr2[o] = f2bf(aR);
    io[o]  = aC;        // row i fully owned by this wave
}

// ---------------- gather2: scalar-uniform (r14 verbatim) ----------------
#define AW 8
__global__ __launch_bounds__(512) void gather2_kernel(
    const u16* __restrict__ xr, const uint64_t* __restrict__ pairs,
    const int* __restrict__ rowptr, float* __restrict__ io, int Nn)
{
    int tid  = threadIdx.x;
    int wave = tid >> 6, lane = tid & 63;
    int i = blockIdx.x * AW + wave;
    if (i >= Nn) return;                       // wave-uniform

    int beg = __builtin_amdgcn_readfirstlane(rowptr[i]);
    int end = __builtin_amdgcn_readfirstlane(rowptr[i + 1]);

    float acc = 0.f;
    for (int b = beg; b < end; b += 8) {
#pragma unroll
        for (int jj = 0; jj < 8; ++jj) {
            uint64_t p = pairs[b + jj];
            int   s  = (int)(u32)p;
            float wr = __uint_as_float((u32)(p >> 32));
            bool valid = (b + jj) < end;
            s = valid ? s : 0;
            float w = valid ? wr : 0.f;
            float v = bf2f(xr[(size_t)s * D + lane]);
            acc = fmaf(v, w, acc);
        }
    }
    size_t o = (size_t)i * D + lane;
    io[o] = acc + io[o];
}

extern "C" void kernel_launch(void* const* d_in, const int* in_sizes, int n_in,
                              void* d_out, int out_size, void* d_ws, size_t ws_size,
                              hipStream_t stream)
{
    const float* x      = (const float*)d_in[0];
    const int*   ei     = (const int*)  d_in[1];
    const float* ew     = (const float*)d_in[2];
    const float* Wrel1  = (const float*)d_in[3];
    const float* brel1  = (const float*)d_in[4];
    const float* Wroot1 = (const float*)d_in[5];
    const float* Wrel2  = (const float*)d_in[6];
    const float* brel2  = (const float*)d_in[7];
    const float* Wroot2 = (const float*)d_in[8];
    float* out = (float*)d_out;

    const int E_ = in_sizes[2];          // 1600000
    const int Nn = in_sizes[0] / D;      // 100000

    // workspace layout — 39.2 MB (r8/r13-proven footprint), + pad after pairs
    char* w = (char*)d_ws;
    size_t off = 0;
    u16*  xr1    = (u16*)(w + off); off += (size_t)Nn * D * sizeof(u16);   // 12.8 MB
    u16*  xr2    = (u16*)(w + off); off += (size_t)Nn * D * sizeof(u16);   // 12.8 MB
    int*  rowptr = (int*)(w + off); off += (size_t)(Nn + 1) * sizeof(int);
    int*  cursor = (int*)(w + off); off += (size_t)Nn * sizeof(int);
    int*  partial= (int*)(w + off); off += 1024 * sizeof(int);
    off = (off + 15) & ~(size_t)15;
    uint64_t* pairs = (uint64_t*)(w + off);                                // 12.8 MB + 64B pad

    const int nchunk  = (Nn + SCAN_CHUNK - 1) / SCAN_CHUNK;
    const int eBlocks = (E_ + 255) / 256;
    const int gemmBlocks = (Nn + GW * GR - 1) / (GW * GR);
    const int g1Blocks   = (Nn + GW - 1) / GW;       // 1 row/wave
    const int g2Blocks   = (Nn + AW - 1) / AW;

    // ---- CSR build (reused by both layers) ----
    (void)hipMemsetAsync(cursor, 0, (size_t)Nn * sizeof(int), stream);
    hist_kernel<<<eBlocks, 256, 0, stream>>>(ei, cursor, E_);
    scan1_kernel<<<nchunk, 256, 0, stream>>>(cursor, rowptr, partial, Nn);
    scan2_kernel<<<1, 1024, 0, stream>>>(partial, nchunk);
    scan3_kernel<<<(Nn + 255) / 256, 256, 0, stream>>>(rowptr, partial, cursor, Nn, E_);
    fill_kernel<<<eBlocks, 256, 0, stream>>>(ei, ew, cursor, pairs, E_);

    // ---- layer 1 pre-transform ----
    gemm_kernel<<<gemmBlocks, 512, 0, stream>>>(x, Wrel1, brel1, Wroot1, xr1, out, Nn);
    // ---- gather1 + relu + layer-2 pre-transform (fused epilogue) ----
    gather1_fused<<<g1Blocks, 512, 0, stream>>>(xr1, pairs, rowptr,
                                                Wrel2, brel2, Wroot2, xr2, out, Nn);
    // ---- gather2 (final) ----
    gather2_kernel<<<g2Blocks, 512, 0, stream>>>(xr2, pairs, rowptr, out, Nn);
}